// Round 1
// 4252.820 us; speedup vs baseline: 2.1161x; 2.1161x over previous
//
#include <hip/hip_runtime.h>
#include <stdint.h>

typedef unsigned short u16;
typedef unsigned int   u32;

// Problem dims
#define T_STEPS 256
#define B_TOT   512
#define EDIM    256
#define NSLOT   128
#define VDIM    256
#define ODIM    256

// Weights in d_ws, bf16 packed PAIR-ALONG-K: u32, entry = (W[2kp][c] lo16, W[2kp+1][c] hi16),
// laid out in per-thread consumption order (uint4 granularity) per shape — see cvt_weights.
// shape A: K=512,C=256 (2 cols/thread, S=8 slices)  -> 65536 u32
// shape B: K=256,C=256 (1 col/thread,  S=4 slices)  -> 32768 u32
// shape C: K=256,C=512 (2 cols/thread, S=4 slices)  -> 65536 u32
#define OFF_W1 0         // A
#define OFF_W2 65536     // B
#define OFF_WR 98304     // B
#define OFF_WW 131072    // C
#define OFF_WO 196608    // A
#define W_TOTAL_U32 262144

// mem LDS: [2 rows][128 slots][132 u32] (128 data u32 (=256 bf16) + 4 pad u32)
#define SLOTU32 132
#define SLOTQ   33                       // uint4 per slot
#define MEMROWU32 (NSLOT * SLOTU32)      // 16896 u32 per row
#define MEMROWQ   (NSLOT * SLOTQ)        // 4224 uint4 per row
#define DLDS (2 * MEMROWU32 * 4)         // 135168 bytes dynamic LDS

__device__ __forceinline__ float bflo(u32 u) { return __uint_as_float(u << 16); }
__device__ __forceinline__ float bfhi(u32 u) { return __uint_as_float(u & 0xffff0000u); }
__device__ __forceinline__ u32 f2bfbits(float f) {
    u32 a = __float_as_uint(f);
    return (a + 0x7fffu + ((a >> 16) & 1u)) >> 16;   // RNE
}
__device__ __forceinline__ u32 pkbf(float lo, float hi) {
    u32 a = __float_as_uint(lo), b = __float_as_uint(hi);
    a = a + 0x7fffu + ((a >> 16) & 1u);
    b = b + 0x7fffu + ((b >> 16) & 1u);
    return (a >> 16) | (b & 0xffff0000u);
}
// single-instruction RNE pack of 2 f32 -> 2 bf16 (lo = src0)
__device__ __forceinline__ u32 cvtpk(float lo, float hi) {
    u32 r;
    asm("v_cvt_pk_bf16_f32 %0, %1, %2" : "=v"(r) : "v"(lo), "v"(hi));
    return r;
}
// D = a.lo*b.lo + a.hi*b.hi + c  (bf16 inputs, fp32 accumulate)
__device__ __forceinline__ float dot2bf(u32 a, u32 b, float c) {
    float d;
    asm("v_dot2_f32_bf16 %0, %1, %2, %3" : "=v"(d) : "v"(a), "v"(b), "v"(c));
    return d;
}

// fp32 -> bf16 pair-along-K packer, emitting per-shape thread-ordered uint4 layout.
// Output uint4 index = blk*1024 + tid; within-uint4 element e.
//  shape A/C: blk = 2*j+half; thread (jg,s); group base kpair = s*32 + ((j+s)&7)*4;
//             kp = base + half*2 + (e>>1); c = jg*2 + (e&1)
//  shape B:   blk = j;        thread (jg,s); kp = base + e; c = jg
__global__ void cvt_weights(const float* __restrict__ W1, const float* __restrict__ W2,
                            const float* __restrict__ Wr, const float* __restrict__ Ww,
                            const float* __restrict__ Wo, u32* __restrict__ dst) {
    int idx = blockIdx.x * 256 + threadIdx.x;     // u32 index
    const float* src; int local, shape, C;
    if      (idx < 65536)  { src = W1; local = idx;          shape = 0; C = 256; }
    else if (idx < 98304)  { src = W2; local = idx - 65536;  shape = 1; C = 256; }
    else if (idx < 131072) { src = Wr; local = idx - 98304;  shape = 1; C = 256; }
    else if (idx < 196608) { src = Ww; local = idx - 131072; shape = 2; C = 512; }
    else                   { src = Wo; local = idx - 196608; shape = 0; C = 256; }
    const int q4 = local >> 2, e = local & 3;
    const int tid = q4 & 1023, blk = q4 >> 10;
    int kp, c;
    if (shape == 1) {                       // 1 col/thread, S=4
        const int j = blk;                  // 0..7
        const int jg = tid >> 2, s = tid & 3;
        kp = s * 32 + ((j + s) & 7) * 4 + e;
        c  = jg;
    } else {                                // 2 cols/thread
        const int j = blk >> 1, half = blk & 1;
        int jg, s;
        if (shape == 0) { jg = tid >> 3; s = tid & 7; }   // S=8
        else            { jg = tid >> 2; s = tid & 3; }   // S=4
        kp = s * 32 + ((j + s) & 7) * 4 + half * 2 + (e >> 1);
        c  = jg * 2 + (e & 1);
    }
    dst[idx] = pkbf(src[(2 * kp) * C + c], src[(2 * kp + 1) * C + c]);
}

// ---- shape A matvec: K=512, C=256, 2 rows. tid = jg*8 + s.
// Shuffle-reduce over 8 slices; s==0 lanes write C as u32 pairs (DST=1) or float2 (DST=2).
template<int DST, bool RELU>
__device__ __forceinline__ void mvA(const uint4* __restrict__ W,
                                    const u16* __restrict__ src,   // [2][512] u16, row stride 64 uint4
                                    const float* __restrict__ bias,
                                    u16* dst,                       // [2][256] u16 (u32 row stride 128)
                                    float* g0, float* g1) {
    const int tid = threadIdx.x;
    const int jg = tid >> 3, s = tid & 7;
    const uint4* a0 = reinterpret_cast<const uint4*>(src) + s * 8;
    const uint4* a1 = a0 + 64;
    float a00 = 0.f, a01 = 0.f, a10 = 0.f, a11 = 0.f;
#pragma unroll 2
    for (int j = 0; j < 8; ++j) {
        const int aj = (j + s) & 7;
        uint4 w0 = W[(2 * j    ) * 1024 + tid];
        uint4 w1 = W[(2 * j + 1) * 1024 + tid];
        uint4 x0 = a0[aj];
        uint4 x1 = a1[aj];
        a00 = dot2bf(x0.x, w0.x, a00); a01 = dot2bf(x0.x, w0.y, a01);
        a00 = dot2bf(x0.y, w0.z, a00); a01 = dot2bf(x0.y, w0.w, a01);
        a00 = dot2bf(x0.z, w1.x, a00); a01 = dot2bf(x0.z, w1.y, a01);
        a00 = dot2bf(x0.w, w1.z, a00); a01 = dot2bf(x0.w, w1.w, a01);
        a10 = dot2bf(x1.x, w0.x, a10); a11 = dot2bf(x1.x, w0.y, a11);
        a10 = dot2bf(x1.y, w0.z, a10); a11 = dot2bf(x1.y, w0.w, a11);
        a10 = dot2bf(x1.z, w1.x, a10); a11 = dot2bf(x1.z, w1.y, a11);
        a10 = dot2bf(x1.w, w1.z, a10); a11 = dot2bf(x1.w, w1.w, a11);
    }
    a00 += __shfl_xor(a00, 1); a00 += __shfl_xor(a00, 2); a00 += __shfl_xor(a00, 4);
    a01 += __shfl_xor(a01, 1); a01 += __shfl_xor(a01, 2); a01 += __shfl_xor(a01, 4);
    a10 += __shfl_xor(a10, 1); a10 += __shfl_xor(a10, 2); a10 += __shfl_xor(a10, 4);
    a11 += __shfl_xor(a11, 1); a11 += __shfl_xor(a11, 2); a11 += __shfl_xor(a11, 4);
    if (s == 0) {
        const float bb0 = bias[2 * jg], bb1 = bias[2 * jg + 1];
        float v00 = a00 + bb0, v01 = a01 + bb1;
        float v10 = a10 + bb0, v11 = a11 + bb1;
        if (RELU) {
            v00 = fmaxf(v00, 0.f); v01 = fmaxf(v01, 0.f);
            v10 = fmaxf(v10, 0.f); v11 = fmaxf(v11, 0.f);
        }
        if constexpr (DST == 1) {
            reinterpret_cast<u32*>(dst)[jg]       = cvtpk(v00, v01);
            reinterpret_cast<u32*>(dst)[128 + jg] = cvtpk(v10, v11);
        } else {
            reinterpret_cast<float2*>(g0)[jg] = make_float2(v00, v01);
            reinterpret_cast<float2*>(g1)[jg] = make_float2(v10, v11);
        }
    }
    if constexpr (DST != 2) __syncthreads();
}

// ---- shape B matvec: K=256, C=256, 2 rows. tid = jg*4 + s (1 col/thread).
template<int AS4, bool BAR>   // AS4 = src row stride in uint4
__device__ __forceinline__ void mvB(const uint4* __restrict__ W,
                                    const u16* __restrict__ src,
                                    const float* __restrict__ bias,
                                    u16* dst, int dstride) {       // dst u16 row stride
    const int tid = threadIdx.x;
    const int jg = tid >> 2, s = tid & 3;
    const uint4* a0 = reinterpret_cast<const uint4*>(src) + s * 8;
    const uint4* a1 = a0 + AS4;
    float r0 = 0.f, r1 = 0.f;
#pragma unroll 4
    for (int j = 0; j < 8; ++j) {
        const int aj = (j + s) & 7;
        uint4 w  = W[j * 1024 + tid];
        uint4 x0 = a0[aj];
        uint4 x1 = a1[aj];
        r0 = dot2bf(x0.x, w.x, r0); r0 = dot2bf(x0.y, w.y, r0);
        r0 = dot2bf(x0.z, w.z, r0); r0 = dot2bf(x0.w, w.w, r0);
        r1 = dot2bf(x1.x, w.x, r1); r1 = dot2bf(x1.y, w.y, r1);
        r1 = dot2bf(x1.z, w.z, r1); r1 = dot2bf(x1.w, w.w, r1);
    }
    r0 += __shfl_xor(r0, 1); r0 += __shfl_xor(r0, 2);
    r1 += __shfl_xor(r1, 1); r1 += __shfl_xor(r1, 2);
    if (s == 0) {
        const float bb = bias[jg];
        dst[jg]           = (u16)f2bfbits(r0 + bb);
        dst[dstride + jg] = (u16)f2bfbits(r1 + bb);
    }
    if constexpr (BAR) __syncthreads();
}

// ---- shape C matvec: K=256, C=512, 2 rows. tid = jg*4 + s (2 cols/thread).
__device__ __forceinline__ void mvC(const uint4* __restrict__ W,
                                    const u16* __restrict__ src,   // row stride 64 uint4 (co part)
                                    const float* __restrict__ bias,
                                    u16* dst) {                    // u32 row stride 256
    const int tid = threadIdx.x;
    const int jg = tid >> 2, s = tid & 3;
    const uint4* a0 = reinterpret_cast<const uint4*>(src) + s * 8;
    const uint4* a1 = a0 + 64;
    float a00 = 0.f, a01 = 0.f, a10 = 0.f, a11 = 0.f;
#pragma unroll 2
    for (int j = 0; j < 8; ++j) {
        const int aj = (j + s) & 7;
        uint4 w0 = W[(2 * j    ) * 1024 + tid];
        uint4 w1 = W[(2 * j + 1) * 1024 + tid];
        uint4 x0 = a0[aj];
        uint4 x1 = a1[aj];
        a00 = dot2bf(x0.x, w0.x, a00); a01 = dot2bf(x0.x, w0.y, a01);
        a00 = dot2bf(x0.y, w0.z, a00); a01 = dot2bf(x0.y, w0.w, a01);
        a00 = dot2bf(x0.z, w1.x, a00); a01 = dot2bf(x0.z, w1.y, a01);
        a00 = dot2bf(x0.w, w1.z, a00); a01 = dot2bf(x0.w, w1.w, a01);
        a10 = dot2bf(x1.x, w0.x, a10); a11 = dot2bf(x1.x, w0.y, a11);
        a10 = dot2bf(x1.y, w0.z, a10); a11 = dot2bf(x1.y, w0.w, a11);
        a10 = dot2bf(x1.z, w1.x, a10); a11 = dot2bf(x1.z, w1.y, a11);
        a10 = dot2bf(x1.w, w1.z, a10); a11 = dot2bf(x1.w, w1.w, a11);
    }
    a00 += __shfl_xor(a00, 1); a00 += __shfl_xor(a00, 2);
    a01 += __shfl_xor(a01, 1); a01 += __shfl_xor(a01, 2);
    a10 += __shfl_xor(a10, 1); a10 += __shfl_xor(a10, 2);
    a11 += __shfl_xor(a11, 1); a11 += __shfl_xor(a11, 2);
    if (s == 0) {
        u32* d32 = reinterpret_cast<u32*>(dst);
        d32[jg]       = cvtpk(a00 + bias[2 * jg], a01 + bias[2 * jg + 1]);
        d32[256 + jg] = cvtpk(a10 + bias[2 * jg], a11 + bias[2 * jg + 1]);
    }
    __syncthreads();
}

__global__ __launch_bounds__(1024, 4)
void ntm_main(const float* __restrict__ x, const u32* __restrict__ Wb,
              const float* __restrict__ b1, const float* __restrict__ b2,
              const float* __restrict__ br, const float* __restrict__ bw,
              const float* __restrict__ bo,
              const float* __restrict__ init_read, const float* __restrict__ mem0,
              float* __restrict__ out) {
    extern __shared__ u16 s_mem[];                 // [2][128][264 u16]
    __shared__ __align__(16) u16 s_cib[2 * 512];   // [x | r] bf16 per row
    __shared__ __align__(16) u16 s_hb [2 * 256];   // h
    __shared__ __align__(16) u16 s_crb[2 * 512];   // [co | r]
    __shared__ __align__(16) u16 s_kvb[2 * 256];   // k
    __shared__ __align__(16) u16 s_ovb[2 * 512];   // [kw | v]
    __shared__ __align__(16) float s_dotr[2 * 128], s_dotw[2 * 128], s_mn2[2 * 128];
    __shared__ __align__(16) float s_wr[2 * 128], s_ww[2 * 128];

    const int tid = threadIdx.x;
    const int b   = blockIdx.x;                    // rows 2b, 2b+1
    u32*   m32  = reinterpret_cast<u32*>(s_mem);
    uint4* memq = reinterpret_cast<uint4*>(s_mem);

    const uint4* W1q = reinterpret_cast<const uint4*>(Wb + OFF_W1);
    const uint4* W2q = reinterpret_cast<const uint4*>(Wb + OFF_W2);
    const uint4* Wrq = reinterpret_cast<const uint4*>(Wb + OFF_WR);
    const uint4* Wwq = reinterpret_cast<const uint4*>(Wb + OFF_WW);
    const uint4* Woq = reinterpret_cast<const uint4*>(Wb + OFF_WO);

    // ---- init: mem0 -> LDS bf16 pairs, init_read -> r slots ----
#pragma unroll 1
    for (int it = 0; it < 32; ++it) {
        int li  = it * 1024 + tid;                 // float2 idx, 2 rows x 16384
        int row = li >> 14, rem = li & 16383;
        int n = rem >> 7, c = rem & 127;
        float2 g = reinterpret_cast<const float2*>(mem0 + ((size_t)(2 * b + row) << 15))[rem];
        m32[row * MEMROWU32 + n * SLOTU32 + c] = pkbf(g.x, g.y);
    }
    if (tid < 256) {
        int row = tid >> 7, i = tid & 127;
        float2 g = reinterpret_cast<const float2*>(init_read + ((size_t)(2 * b + row) << 8))[i];
        reinterpret_cast<u32*>(s_cib)[row * 256 + 128 + i] = pkbf(g.x, g.y);
    }
    // prefetch x_0
    float2 gx = make_float2(0.f, 0.f);
    if (tid < 256) {
        int row = tid >> 7, i = tid & 127;
        gx = reinterpret_cast<const float2*>(x + (size_t)(2 * b + row) * EDIM)[i];
    }
    __syncthreads();

#pragma unroll 1
    for (int t = 0; t < T_STEPS; ++t) {
        // ---- commit prefetched x_t ----
        if (tid < 256) {
            int row = tid >> 7, i = tid & 127;
            reinterpret_cast<u32*>(s_cib)[row * 256 + i] = cvtpk(gx.x, gx.y);
        }
        __syncthreads();

        // ---- GEMM chain ----
        mvA<1, true>(W1q, s_cib, b1, s_hb, nullptr, nullptr);

        // prefetch x_{t+1}; latency hides under the rest of the step
        if (t + 1 < T_STEPS && tid < 256) {
            int row = tid >> 7, i = tid & 127;
            gx = reinterpret_cast<const float2*>(
                x + (size_t)(t + 1) * (B_TOT * EDIM) + (size_t)(2 * b + row) * EDIM)[i];
        }

        mvB<32, true >(W2q, s_hb,  b2, s_crb, 512);
        mvB<64, false>(Wrq, s_crb, br, s_kvb, 256);    // no barrier: mvC only reads s_crb
        mvC(Wwq, s_crb, bw, s_ovb);

        // ---- pass1: dr=k.mem, dw=kw.mem, s2=|mem|^2 ; thread = (row, n, vq) ----
        {
            const int row = tid >> 9, n = (tid >> 2) & 127, vq = tid & 3;
            const uint4* mq  = memq + row * MEMROWQ + n * SLOTQ;
            const uint4* kq  = reinterpret_cast<const uint4*>(s_kvb) + row * 32;
            const uint4* kwq = reinterpret_cast<const uint4*>(s_ovb) + row * 64;
            float dr = 0.f, dw = 0.f, s2 = 0.f;
#pragma unroll
            for (int ih = 0; ih < 4; ++ih) {
                const int e = vq * 2 + ih * 8;     // bank-spread interleave (2-way max)
                uint4 m0 = mq[e], m1 = mq[e + 1];
                uint4 ka = kq[e], kb = kq[e + 1];
                uint4 wa = kwq[e], wb = kwq[e + 1];
                dr = dot2bf(m0.x, ka.x, dr); dr = dot2bf(m0.y, ka.y, dr);
                dr = dot2bf(m0.z, ka.z, dr); dr = dot2bf(m0.w, ka.w, dr);
                dr = dot2bf(m1.x, kb.x, dr); dr = dot2bf(m1.y, kb.y, dr);
                dr = dot2bf(m1.z, kb.z, dr); dr = dot2bf(m1.w, kb.w, dr);
                dw = dot2bf(m0.x, wa.x, dw); dw = dot2bf(m0.y, wa.y, dw);
                dw = dot2bf(m0.z, wa.z, dw); dw = dot2bf(m0.w, wa.w, dw);
                dw = dot2bf(m1.x, wb.x, dw); dw = dot2bf(m1.y, wb.y, dw);
                dw = dot2bf(m1.z, wb.z, dw); dw = dot2bf(m1.w, wb.w, dw);
                s2 = dot2bf(m0.x, m0.x, s2); s2 = dot2bf(m0.y, m0.y, s2);
                s2 = dot2bf(m0.z, m0.z, s2); s2 = dot2bf(m0.w, m0.w, s2);
                s2 = dot2bf(m1.x, m1.x, s2); s2 = dot2bf(m1.y, m1.y, s2);
                s2 = dot2bf(m1.z, m1.z, s2); s2 = dot2bf(m1.w, m1.w, s2);
            }
            dr += __shfl_xor(dr, 1); dr += __shfl_xor(dr, 2);
            dw += __shfl_xor(dw, 1); dw += __shfl_xor(dw, 2);
            s2 += __shfl_xor(s2, 1); s2 += __shfl_xor(s2, 2);
            if (vq == 0) {
                s_dotr[row * 128 + n] = dr;
                s_dotw[row * 128 + n] = dw;
                s_mn2 [row * 128 + n] = s2;
            }
        }
        __syncthreads();

        // ---- softmax (cosine addressing), one wave per (row,key) ----
        if (tid < 256) {
            const int row = tid >> 7, key = (tid >> 6) & 1, lane = tid & 63;
            const uint2* kv2 = key ? (reinterpret_cast<const uint2*>(s_ovb) + row * 128)
                                   : (reinterpret_cast<const uint2*>(s_kvb) + row * 64);
            uint2 kk = kv2[lane];
            float q = dot2bf(kk.x, kk.x, 0.f);
            q = dot2bf(kk.y, kk.y, q);
#pragma unroll
            for (int m = 1; m < 64; m <<= 1) q += __shfl_xor(q, m);
            float kn = fmaxf(sqrtf(q), 1e-8f);
            const float* dot = (key ? s_dotw : s_dotr) + row * 128;
            const float* mn2 = s_mn2 + row * 128;
            int n0 = lane, n1 = lane + 64;
            float mn0 = fmaxf(sqrtf(mn2[n0]), 1e-8f);
            float mn1 = fmaxf(sqrtf(mn2[n1]), 1e-8f);
            float av0 = dot[n0] / (kn * mn0);
            float av1 = dot[n1] / (kn * mn1);
            float mx = fmaxf(av0, av1);
#pragma unroll
            for (int m = 1; m < 64; m <<= 1) mx = fmaxf(mx, __shfl_xor(mx, m));
            float e0 = __expf(av0 - mx), e1 = __expf(av1 - mx);
            float sm = e0 + e1;
#pragma unroll
            for (int m = 1; m < 64; m <<= 1) sm += __shfl_xor(sm, m);
            float inv = 1.0f / sm;
            float* wdst = (key ? s_ww : s_wr) + row * 128;
            wdst[n0] = e0 * inv;
            wdst[n1] = e1 * inv;
        }
        __syncthreads();

        // ---- pass2a: r = sum_n w[n]*mem[n,:] ; thread = (row, vc, ns), shuffle over ns ----
        {
            const int row = tid >> 9, vc = (tid >> 2) & 127, ns = tid & 3;
            const u32* mrow = m32 + row * MEMROWU32;
            const float* wp = s_wr + row * 128;
            float r0 = 0.f, r1 = 0.f;
#pragma unroll 4
            for (int j = 0; j < 32; ++j) {
                const int slot = ns + 4 * j;       // slot interleave: 2-way max conflicts
                u32 m = mrow[slot * SLOTU32 + vc];
                float wj = wp[slot];
                r0 = fmaf(bflo(m), wj, r0);
                r1 = fmaf(bfhi(m), wj, r1);
            }
            r0 += __shfl_xor(r0, 1); r0 += __shfl_xor(r0, 2);
            r1 += __shfl_xor(r1, 1); r1 += __shfl_xor(r1, 2);
            if (ns == 0) {
                u32 p = cvtpk(r0, r1);
                reinterpret_cast<u32*>(s_cib)[row * 256 + 128 + vc] = p;
                reinterpret_cast<u32*>(s_crb)[row * 256 + 128 + vc] = p;
            }
        }
        __syncthreads();   // fences pass2a mem reads against pass2b mem writes

        // ---- pass2b: mem += ww[n]*v ; thread = (row, n, vq) ----
        {
            const int row = tid >> 9, n = (tid >> 2) & 127, vq = tid & 3;
            uint4* mq = memq + row * MEMROWQ + n * SLOTQ;
            const uint4* vv = reinterpret_cast<const uint4*>(s_ovb) + row * 64 + 32;
            const float wwn = s_ww[row * 128 + n];
#pragma unroll
            for (int ih = 0; ih < 4; ++ih) {
                const int e = vq * 2 + ih * 8;
                uint4 m0 = mq[e], m1 = mq[e + 1];
                uint4 v0 = vv[e], v1 = vv[e + 1];
                u32* pm0 = reinterpret_cast<u32*>(&m0);
                const u32* pv0 = reinterpret_cast<const u32*>(&v0);
#pragma unroll
                for (int q = 0; q < 4; ++q) {
                    float o0 = fmaf(bflo(pv0[q]), wwn, bflo(pm0[q]));
                    float o1 = fmaf(bfhi(pv0[q]), wwn, bfhi(pm0[q]));
                    pm0[q] = cvtpk(o0, o1);
                }
                u32* pm1 = reinterpret_cast<u32*>(&m1);
                const u32* pv1 = reinterpret_cast<const u32*>(&v1);
#pragma unroll
                for (int q = 0; q < 4; ++q) {
                    float o0 = fmaf(bflo(pv1[q]), wwn, bflo(pm1[q]));
                    float o1 = fmaf(bfhi(pv1[q]), wwn, bfhi(pm1[q]));
                    pm1[q] = cvtpk(o0, o1);
                }
                mq[e] = m0; mq[e + 1] = m1;
            }
        }
        __syncthreads();

        // ---- out_t = [co | r] @ Wo + bo -> global (no trailing barrier) ----
        mvA<2, false>(Woq, s_crb, bo, nullptr,
                      out + (size_t)t * (B_TOT * ODIM) + (size_t)(2 * b) * ODIM,
                      out + (size_t)t * (B_TOT * ODIM) + (size_t)(2 * b + 1) * ODIM);
    }
}

extern "C" void kernel_launch(void* const* d_in, const int* in_sizes, int n_in,
                              void* d_out, int out_size, void* d_ws, size_t ws_size,
                              hipStream_t stream) {
    (void)in_sizes; (void)n_in; (void)out_size; (void)ws_size;
    const float* x         = (const float*)d_in[0];
    const float* W1        = (const float*)d_in[1];
    const float* b1        = (const float*)d_in[2];
    const float* W2        = (const float*)d_in[3];
    const float* b2        = (const float*)d_in[4];
    const float* Wr        = (const float*)d_in[5];
    const float* br        = (const float*)d_in[6];
    const float* Ww        = (const float*)d_in[7];
    const float* bw        = (const float*)d_in[8];
    const float* Wo        = (const float*)d_in[9];
    const float* bo        = (const float*)d_in[10];
    const float* init_read = (const float*)d_in[11];
    const float* mem0      = (const float*)d_in[12];
    float* out = (float*)d_out;
    u32* wb = (u32*)d_ws;

    hipLaunchKernelGGL(cvt_weights, dim3(W_TOTAL_U32 / 256), dim3(256), 0, stream,
                       W1, W2, Wr, Ww, Wo, wb);

    (void)hipFuncSetAttribute(reinterpret_cast<const void*>(ntm_main),
                              hipFuncAttributeMaxDynamicSharedMemorySize, DLDS);

    hipLaunchKernelGGL(ntm_main, dim3(B_TOT / 2), dim3(1024), DLDS, stream,
                       x, wb, b1, b2, br, bw, bo, init_read, mem0, out);
}